// Round 11
// baseline (181.657 us; speedup 1.0000x reference)
//
#include <hip/hip_runtime.h>
#include <hip/hip_bf16.h>
#include <stdint.h>

// ---------------------------------------------------------------------------
// GumbelQuantizer: z[32768,256] fp32, emb[1024,256] fp32 ->
//   out0 = softmax((-d + gumbel)) @ emb  (straight-through == quantized)
//   out1 = 1.25 * mean((quantized - z)^2)
// s_k = 2 z.e_k - |e_k|^2 (row-constant -|z|^2 cancels). Gumbel via exact JAX
// threefry2x32; e^g = rcp(-log2 u) (global 1/ln2 cancels in softmax).
//
// R11: 4 barrier domains/CU with R7's per-wave ILP intact. R10 failed by
// halving per-wave MFMA chains; R11 keeps them: 1024 blocks x 256 thr
// (4 waves) x 32 z-rows (G0/G1 even/odd interleave, R10-validated threefry
// pairing). Per wave/tile: k-stripe 32, m1 = 4 chains x 8 MFMA (=R7),
// 8 ciphers, m2 = 4 chains (d-stripe 64). LDS 32KB (zb 16K + P dbuf 16K)
// -> 4 blocks/CU. launch_bounds(256,4) -> 128-VGPR budget (empirical rule:
// budget = 512/(arg2 * wavesPerBlock/4) regs). mb/nb batched 8-at-a-time
// to stay ~119 regs peak. Region order = R7's proven one.
// ---------------------------------------------------------------------------

typedef __bf16 bf16x8 __attribute__((ext_vector_type(8)));
typedef float  f32x4  __attribute__((ext_vector_type(4)));

#define MFMA16(A,B,C) __builtin_amdgcn_mfma_f32_16x16x32_bf16((A),(B),(C),0,0,0)

struct TF2 { uint32_t a, b; };

__host__ __device__ constexpr uint32_t rotl32(uint32_t v, int r){ return (v<<r)|(v>>(32-r)); }

// Threefry-2x32, 20 rounds — exact JAX implementation.
__host__ __device__ constexpr TF2 tf2x32(uint32_t k0, uint32_t k1, uint32_t x0, uint32_t x1){
  const uint32_t k2 = k0 ^ k1 ^ 0x1BD11BDAu;
  x0 += k0; x1 += k1;
  x0 += x1; x1 = rotl32(x1,13); x1 ^= x0;
  x0 += x1; x1 = rotl32(x1,15); x1 ^= x0;
  x0 += x1; x1 = rotl32(x1,26); x1 ^= x0;
  x0 += x1; x1 = rotl32(x1, 6); x1 ^= x0;
  x0 += k1; x1 += k2 + 1u;
  x0 += x1; x1 = rotl32(x1,17); x1 ^= x0;
  x0 += x1; x1 = rotl32(x1,29); x1 ^= x0;
  x0 += x1; x1 = rotl32(x1,16); x1 ^= x0;
  x0 += x1; x1 = rotl32(x1,24); x1 ^= x0;
  x0 += k2; x1 += k0 + 2u;
  x0 += x1; x1 = rotl32(x1,13); x1 ^= x0;
  x0 += x1; x1 = rotl32(x1,15); x1 ^= x0;
  x0 += x1; x1 = rotl32(x1,26); x1 ^= x0;
  x0 += x1; x1 = rotl32(x1, 6); x1 ^= x0;
  x0 += k0; x1 += k1 + 3u;
  x0 += x1; x1 = rotl32(x1,17); x1 ^= x0;
  x0 += x1; x1 = rotl32(x1,29); x1 ^= x0;
  x0 += x1; x1 = rotl32(x1,16); x1 ^= x0;
  x0 += x1; x1 = rotl32(x1,24); x1 ^= x0;
  x0 += k1; x1 += k2 + 4u;
  x0 += x1; x1 = rotl32(x1,13); x1 ^= x0;
  x0 += x1; x1 = rotl32(x1,15); x1 ^= x0;
  x0 += x1; x1 = rotl32(x1,26); x1 ^= x0;
  x0 += x1; x1 = rotl32(x1, 6); x1 ^= x0;
  x0 += k2; x1 += k0 + 5u;
  return {x0, x1};
}

// gkey = fold_in(key(0), 1) = threefry((0,0), (0,1)) — compile-time.
constexpr TF2 GKEY = tf2x32(0u, 0u, 0u, 1u);

__device__ __forceinline__ unsigned short f2bf(float f){
  __bf16 h = (__bf16)f;
  return __builtin_bit_cast(unsigned short, h);
}

// exp(gumbel) up to a global constant: 1/(-log2 u), u = JAX uniform(tiny,1)
__device__ __forceinline__ float gumbel_w(uint32_t bits){
  float uf = __uint_as_float((bits >> 9) | 0x3f800000u) - 1.0f;
  float u  = fmaxf(uf, 1.17549435e-38f);
  return __builtin_amdgcn_rcpf(-__log2f(u));
}

// ---------------------------------------------------------------------------
// Prep: bf16 E [1024][256], bf16 E^T [256][1024], |e_k|^2 fp32 [1024]
// ---------------------------------------------------------------------------
__global__ void gq_prep(const float* __restrict__ emb, unsigned short* __restrict__ Eb,
                        unsigned short* __restrict__ ETb, float* __restrict__ enorm)
{
  const int r = blockIdx.x;       // 1024 emb rows
  const int t = threadIdx.x;      // 256 threads = one row
  float e = emb[r*256 + t];
  unsigned short h = f2bf(e);
  Eb[r*256 + t] = h;
  ETb[t*1024 + r] = h;
  float sq = e*e;
  #pragma unroll
  for (int o = 32; o > 0; o >>= 1) sq += __shfl_down(sq, o);
  __shared__ float ws4[4];
  if ((t & 63) == 0) ws4[t >> 6] = sq;
  __syncthreads();
  if (t == 0) enorm[r] = ws4[0] + ws4[1] + ws4[2] + ws4[3];
}

// ---------------------------------------------------------------------------
// Main: 1024 blocks x 256 threads (4 waves), 4 blocks/CU.
// C-row r (0..31) <-> global z row g(r) = b*16 + (r>>1) + (r&1)*16384
// (even = G0 t, odd = G1 t+16384 -> threefry pair (idx, idx+2^24)).
// LDS: zb = bf16 z [32][256] XOR-swizzled   16384 B
//      Pl = bf16 P [2][32][128] swizzled    16384 B (double-buffered)
// Per 128-k tile: wave w owns k-stripe [w*32,+32) (m1/gumbel, 2 x 16-col
// MFMA chains x 2 row-tiles) and d-cols [w*64,+64) (m2, 4 ct chains).
// ---------------------------------------------------------------------------
__global__ __launch_bounds__(256, 4)   // 4 blocks/CU, 128-VGPR budget
void gq_main(
    const float* __restrict__ z, const unsigned short* __restrict__ Eb,
    const unsigned short* __restrict__ ETb, const float* __restrict__ enorm,
    float* __restrict__ out, float* __restrict__ partials)
{
  __shared__ __align__(16) unsigned char sm[16384 + 16384];
  unsigned char* zb  = sm;                             // bf16 z, swizzled
  unsigned char* Pl0 = sm + 16384;                     // P dbuf, swizzled
  float* denomW = (float*)(sm + 16384);                // reuse P: [4][32]
  float* denomF = (float*)(sm + 16384 + 512);          // [32]
  float* lsumW  = (float*)(sm + 16384 + 512 + 128);    // [4]

  const int tid  = threadIdx.x;
  const int lane = tid & 63;
  const int wv   = tid >> 6;        // wave 0..3
  const int col  = lane & 15;
  const int hi   = lane >> 4;       // 0..3
  const int b16g = blockIdx.x * 16; // G0 row base

  // ---- stage z: 32 C-rows fp32 -> bf16 swizzled zb ----
  #pragma unroll
  for (int j = 0; j < 4; ++j) {
    int lin = j*256 + tid;              // 0..1023 float8-chunks
    int row = lin >> 5;                 // 0..31
    int c8  = lin & 31;
    int grow = b16g + (row >> 1) + (row & 1) * 16384;
    const float4* src = reinterpret_cast<const float4*>(z + (size_t)grow*256 + c8*8);
    float4 v0 = src[0], v1 = src[1];
    uint32_t w0 = (uint32_t)f2bf(v0.x) | ((uint32_t)f2bf(v0.y) << 16);
    uint32_t w1 = (uint32_t)f2bf(v0.z) | ((uint32_t)f2bf(v0.w) << 16);
    uint32_t w2 = (uint32_t)f2bf(v1.x) | ((uint32_t)f2bf(v1.y) << 16);
    uint32_t w3 = (uint32_t)f2bf(v1.z) | ((uint32_t)f2bf(v1.w) << 16);
    int boff = (row*512 + c8*16) ^ ((row & 7) << 4);
    uint32_t* p = reinterpret_cast<uint32_t*>(zb + boff);
    p[0] = w0; p[1] = w1; p[2] = w2; p[3] = w3;
  }
  __syncthreads();

  f32x4 accQ[2][4] = {};      // 2 row-tiles x 4 d-col-tiles (32 regs)
  float dn[2][4] = {};        // denominator partials
  float lsum = 0.0f;

  #pragma unroll 1
  for (int kt = 0; kt < 8; ++kt) {
    const int ke0 = kt*128 + wv*32;     // this wave's 32-wide k-stripe
    unsigned char* Pl = Pl0 + (kt & 1)*8192;

    // ---- region 1: mb batch-0 + enorms + ciphers + m1 (2 kc passes) ----
    const unsigned short* eb0 = Eb + (size_t)(ke0 + col)*256 + hi*8;
    const unsigned short* eb1 = eb0 + 16*256;
    bf16x8 mb[8];
    #pragma unroll
    for (int kk = 0; kk < 8; ++kk)
      mb[kk] = *reinterpret_cast<const bf16x8*>(eb0 + kk*32);

    float enk0 = enorm[ke0 + col];
    float enk1 = enorm[ke0 + 16 + col];

    TF2 c[2][2][2];           // (row-tile, kc, pair) — pure VALU, covers mb
    #pragma unroll
    for (int rt = 0; rt < 2; ++rt)
      #pragma unroll
      for (int kc = 0; kc < 2; ++kc)
        #pragma unroll
        for (int p = 0; p < 2; ++p) {
          uint32_t t0 = (uint32_t)(b16g + rt*8 + hi*2 + p);
          uint32_t idx = t0*1024u + (uint32_t)(ke0 + kc*16 + col);
          c[rt][kc][p] = tf2x32(GKEY.a, GKEY.b, idx, idx + (1u<<24));
        }

    f32x4 aS[2][2] = {};      // (row-tile, kc)
    __builtin_amdgcn_s_setprio(1);
    #pragma unroll
    for (int kk = 0; kk < 8; ++kk) {
      #pragma unroll
      for (int rt = 0; rt < 2; ++rt) {
        int arow = rt*16 + col;
        int aoff = (arow*512 + kk*64 + hi*16) ^ ((arow & 7) << 4);
        bf16x8 af = *reinterpret_cast<const bf16x8*>(zb + aoff);
        aS[rt][0] = MFMA16(af, mb[kk], aS[rt][0]);
      }
    }
    __builtin_amdgcn_s_setprio(0);
    #pragma unroll
    for (int kk = 0; kk < 8; ++kk)                 // mb batch-1 (reuses regs)
      mb[kk] = *reinterpret_cast<const bf16x8*>(eb1 + kk*32);
    __builtin_amdgcn_s_setprio(1);
    #pragma unroll
    for (int kk = 0; kk < 8; ++kk) {
      #pragma unroll
      for (int rt = 0; rt < 2; ++rt) {
        int arow = rt*16 + col;
        int aoff = (arow*512 + kk*64 + hi*16) ^ ((arow & 7) << 4);
        bf16x8 af = *reinterpret_cast<const bf16x8*>(zb + aoff);
        aS[rt][1] = MFMA16(af, mb[kk], aS[rt][1]);
      }
    }
    __builtin_amdgcn_s_setprio(0);

    // ---- region 2: nbA loads (ct 0,1) + exp/gumbel/store-P ----
    const unsigned short* etb = ETb + (size_t)(wv*64 + col)*1024 + kt*128 + hi*8;
    bf16x8 nbA[8];
    #pragma unroll
    for (int kk = 0; kk < 4; ++kk) {
      nbA[kk]   = *reinterpret_cast<const bf16x8*>(etb + kk*32);            // ct0
      nbA[kk+4] = *reinterpret_cast<const bf16x8*>(etb + 16*1024 + kk*32);  // ct1
    }

    #pragma unroll
    for (int rt = 0; rt < 2; ++rt) {
      #pragma unroll
      for (int kc = 0; kc < 2; ++kc) {
        float enk = kc ? enk1 : enk0;
        int kl2 = (wv*32 + kc*16 + col)*2;
        #pragma unroll
        for (int rg = 0; rg < 4; ++rg) {
          int row = rt*16 + hi*4 + rg;
          uint32_t bits = (rg & 1) ? c[rt][kc][rg>>1].b : c[rt][kc][rg>>1].a;
          float pv = __expf(2.0f*aS[rt][kc][rg] - enk) * gumbel_w(bits);
          dn[rt][rg] += pv;
          *(unsigned short*)(Pl + ((row*256 + kl2) ^ ((row & 7) << 4))) = f2bf(pv);
        }
      }
    }
    __syncthreads();

    // ---- region 3: nbB issue + m2 (2 halves) ----
    bf16x8 nbB[8];
    #pragma unroll
    for (int kk = 0; kk < 4; ++kk) {
      nbB[kk]   = *reinterpret_cast<const bf16x8*>(etb + 32*1024 + kk*32);  // ct2
      nbB[kk+4] = *reinterpret_cast<const bf16x8*>(etb + 48*1024 + kk*32);  // ct3
    }
    __builtin_amdgcn_s_setprio(1);
    #pragma unroll
    for (int kk = 0; kk < 4; ++kk) {
      #pragma unroll
      for (int rt = 0; rt < 2; ++rt) {
        int prow = rt*16 + col;
        int poff = (prow*256 + kk*64 + hi*16) ^ ((prow & 7) << 4);
        bf16x8 af = *reinterpret_cast<const bf16x8*>(Pl + poff);
        accQ[rt][0] = MFMA16(af, nbA[kk],   accQ[rt][0]);
        accQ[rt][1] = MFMA16(af, nbA[kk+4], accQ[rt][1]);
        accQ[rt][2] = MFMA16(af, nbB[kk],   accQ[rt][2]);
        accQ[rt][3] = MFMA16(af, nbB[kk+4], accQ[rt][3]);
      }
    }
    __builtin_amdgcn_s_setprio(0);
    // no second barrier: next iteration writes the other P buffer
  }
  __syncthreads();   // protect reduction-scratch reuse of Pl

  // ---- denominator: reduce over 16 col-lanes, then 4 waves via LDS ----
  #pragma unroll
  for (int rt = 0; rt < 2; ++rt)
    #pragma unroll
    for (int rg = 0; rg < 4; ++rg) {
      float v = dn[rt][rg];
      v += __shfl_xor(v, 1);
      v += __shfl_xor(v, 2);
      v += __shfl_xor(v, 4);
      v += __shfl_xor(v, 8);
      dn[rt][rg] = v;
    }
  if (col == 0) {
    #pragma unroll
    for (int rt = 0; rt < 2; ++rt)
      #pragma unroll
      for (int rg = 0; rg < 4; ++rg)
        denomW[wv*32 + rt*16 + hi*4 + rg] = dn[rt][rg];
  }
  __syncthreads();
  if (tid < 32) {
    float s = denomW[tid] + denomW[32+tid] + denomW[64+tid] + denomW[96+tid];
    denomF[tid] = __builtin_amdgcn_rcpf(s);
  }
  __syncthreads();

  // ---- epilogue: normalize, write out0, loss partial ----
  #pragma unroll
  for (int rt = 0; rt < 2; ++rt) {
    #pragma unroll
    for (int rg = 0; rg < 4; ++rg) {
      int row = rt*16 + hi*4 + rg;
      float rd = denomF[row];
      int grow = b16g + (row >> 1) + (row & 1)*16384;
      float* orow = out + (size_t)grow*256;
      const float* zrow = z + (size_t)grow*256;
      #pragma unroll
      for (int ct = 0; ct < 4; ++ct) {
        int d = wv*64 + ct*16 + col;
        float q  = accQ[rt][ct][rg] * rd;
        float zv = zrow[d];
        float df = q - zv;
        orow[d] = zv + df;          // straight-through value == quantized
        lsum += df*df;
      }
    }
  }
  #pragma unroll
  for (int o = 32; o > 0; o >>= 1) lsum += __shfl_down(lsum, o);
  if (lane == 0) lsumW[wv] = lsum;
  __syncthreads();
  if (tid == 0) {
    partials[blockIdx.x] = lsumW[0] + lsumW[1] + lsumW[2] + lsumW[3];
  }
}

// ---------------------------------------------------------------------------
// Final: loss = 1.25 * sum(partials[0..1024)) / 2^23
// ---------------------------------------------------------------------------
__global__ void gq_final(const float* __restrict__ partials, float* __restrict__ out)
{
  const int t = threadIdx.x;   // 512
  float v = partials[t] + partials[t + 512];
  #pragma unroll
  for (int o = 32; o > 0; o >>= 1) v += __shfl_down(v, o);
  __shared__ float ws8[8];
  if ((t & 63) == 0) ws8[t >> 6] = v;
  __syncthreads();
  if (t == 0) {
    float s = 0.f;
    #pragma unroll
    for (int i = 0; i < 8; ++i) s += ws8[i];
    out[8388608] = 1.25f * s * (1.0f / 8388608.0f);
  }
}

extern "C" void kernel_launch(void* const* d_in, const int* in_sizes, int n_in,
                              void* d_out, int out_size, void* d_ws, size_t ws_size,
                              hipStream_t stream)
{
  const float* z   = (const float*)d_in[0];   // [32,1024,256]
  const float* emb = (const float*)d_in[1];   // [1024,256]
  float* out = (float*)d_out;                 // 8388608 + 1
  char* ws = (char*)d_ws;
  unsigned short* Eb  = (unsigned short*)ws;               // 524288 B
  unsigned short* ETb = (unsigned short*)(ws + 524288);    // 524288 B
  float* enorm    = (float*)(ws + 1048576);                // 4096 B
  float* partials = (float*)(ws + 1048576 + 4096);         // 4096 B

  gq_prep<<<1024, 256, 0, stream>>>(emb, Eb, ETb, enorm);
  gq_main<<<1024, 256, 0, stream>>>(z, Eb, ETb, enorm, out, partials);
  gq_final<<<1, 512, 0, stream>>>(partials, out);
}

// Round 12
// 134.479 us; speedup vs baseline: 1.3508x; 1.3508x over previous
//
#include <hip/hip_runtime.h>
#include <hip/hip_bf16.h>
#include <stdint.h>

// ---------------------------------------------------------------------------
// GumbelQuantizer: z[32768,256] fp32, emb[1024,256] fp32 ->
//   out0 = softmax((-d + gumbel)) @ emb  (straight-through == quantized)
//   out1 = 1.25 * mean((quantized - z)^2)
// s_k = 2 z.e_k - |e_k|^2 (row-constant -|z|^2 cancels). Gumbel via exact JAX
// threefry2x32; e^g = rcp(-log2 u) (global 1/ln2 cancels in softmax).
//
// R12: R11 with the CORRECT register-budget declaration. Empirical rule from
// R1-R11 on this toolchain: VGPR budget = 256/arg2 of __launch_bounds__,
// independent of block size ((512,2)->128 ok; (512,4),(256,4)->64 spill).
// R11 needed ~119 regs but declared (256,4) -> 64-reg budget -> 192MB scratch
// spill. This round: (256,2) -> 128-reg budget. LDS 32KB + 128 regs both
// land at 4 blocks/CU = 4 independent barrier domains with R7-grade per-wave
// ILP (m1 = 4 x 8-deep MFMA chains, 32-wide k-stripe, batched mb/nb).
// ---------------------------------------------------------------------------

typedef __bf16 bf16x8 __attribute__((ext_vector_type(8)));
typedef float  f32x4  __attribute__((ext_vector_type(4)));

#define MFMA16(A,B,C) __builtin_amdgcn_mfma_f32_16x16x32_bf16((A),(B),(C),0,0,0)

struct TF2 { uint32_t a, b; };

__host__ __device__ constexpr uint32_t rotl32(uint32_t v, int r){ return (v<<r)|(v>>(32-r)); }

// Threefry-2x32, 20 rounds — exact JAX implementation.
__host__ __device__ constexpr TF2 tf2x32(uint32_t k0, uint32_t k1, uint32_t x0, uint32_t x1){
  const uint32_t k2 = k0 ^ k1 ^ 0x1BD11BDAu;
  x0 += k0; x1 += k1;
  x0 += x1; x1 = rotl32(x1,13); x1 ^= x0;
  x0 += x1; x1 = rotl32(x1,15); x1 ^= x0;
  x0 += x1; x1 = rotl32(x1,26); x1 ^= x0;
  x0 += x1; x1 = rotl32(x1, 6); x1 ^= x0;
  x0 += k1; x1 += k2 + 1u;
  x0 += x1; x1 = rotl32(x1,17); x1 ^= x0;
  x0 += x1; x1 = rotl32(x1,29); x1 ^= x0;
  x0 += x1; x1 = rotl32(x1,16); x1 ^= x0;
  x0 += x1; x1 = rotl32(x1,24); x1 ^= x0;
  x0 += k2; x1 += k0 + 2u;
  x0 += x1; x1 = rotl32(x1,13); x1 ^= x0;
  x0 += x1; x1 = rotl32(x1,15); x1 ^= x0;
  x0 += x1; x1 = rotl32(x1,26); x1 ^= x0;
  x0 += x1; x1 = rotl32(x1, 6); x1 ^= x0;
  x0 += k0; x1 += k1 + 3u;
  x0 += x1; x1 = rotl32(x1,17); x1 ^= x0;
  x0 += x1; x1 = rotl32(x1,29); x1 ^= x0;
  x0 += x1; x1 = rotl32(x1,16); x1 ^= x0;
  x0 += x1; x1 = rotl32(x1,24); x1 ^= x0;
  x0 += k1; x1 += k2 + 4u;
  x0 += x1; x1 = rotl32(x1,13); x1 ^= x0;
  x0 += x1; x1 = rotl32(x1,15); x1 ^= x0;
  x0 += x1; x1 = rotl32(x1,26); x1 ^= x0;
  x0 += x1; x1 = rotl32(x1, 6); x1 ^= x0;
  x0 += k2; x1 += k0 + 5u;
  return {x0, x1};
}

// gkey = fold_in(key(0), 1) = threefry((0,0), (0,1)) — compile-time.
constexpr TF2 GKEY = tf2x32(0u, 0u, 0u, 1u);

__device__ __forceinline__ unsigned short f2bf(float f){
  __bf16 h = (__bf16)f;
  return __builtin_bit_cast(unsigned short, h);
}

// exp(gumbel) up to a global constant: 1/(-log2 u), u = JAX uniform(tiny,1)
__device__ __forceinline__ float gumbel_w(uint32_t bits){
  float uf = __uint_as_float((bits >> 9) | 0x3f800000u) - 1.0f;
  float u  = fmaxf(uf, 1.17549435e-38f);
  return __builtin_amdgcn_rcpf(-__log2f(u));
}

// ---------------------------------------------------------------------------
// Prep: bf16 E [1024][256], bf16 E^T [256][1024], |e_k|^2 fp32 [1024]
// ---------------------------------------------------------------------------
__global__ void gq_prep(const float* __restrict__ emb, unsigned short* __restrict__ Eb,
                        unsigned short* __restrict__ ETb, float* __restrict__ enorm)
{
  const int r = blockIdx.x;       // 1024 emb rows
  const int t = threadIdx.x;      // 256 threads = one row
  float e = emb[r*256 + t];
  unsigned short h = f2bf(e);
  Eb[r*256 + t] = h;
  ETb[t*1024 + r] = h;
  float sq = e*e;
  #pragma unroll
  for (int o = 32; o > 0; o >>= 1) sq += __shfl_down(sq, o);
  __shared__ float ws4[4];
  if ((t & 63) == 0) ws4[t >> 6] = sq;
  __syncthreads();
  if (t == 0) enorm[r] = ws4[0] + ws4[1] + ws4[2] + ws4[3];
}

// ---------------------------------------------------------------------------
// Main: 1024 blocks x 256 threads (4 waves), 4 blocks/CU.
// C-row r (0..31) <-> global z row g(r) = b*16 + (r>>1) + (r&1)*16384
// (even = G0 t, odd = G1 t+16384 -> threefry pair (idx, idx+2^24)).
// LDS: zb = bf16 z [32][256] XOR-swizzled   16384 B
//      Pl = bf16 P [2][32][128] swizzled    16384 B (double-buffered)
// Per 128-k tile: wave w owns k-stripe [w*32,+32) (m1/gumbel, 2 x 16-col
// MFMA chains x 2 row-tiles) and d-cols [w*64,+64) (m2, 4 ct chains).
// ---------------------------------------------------------------------------
__global__ __launch_bounds__(256, 2)   // budget = 256/2 = 128 VGPR (empirical)
void gq_main(
    const float* __restrict__ z, const unsigned short* __restrict__ Eb,
    const unsigned short* __restrict__ ETb, const float* __restrict__ enorm,
    float* __restrict__ out, float* __restrict__ partials)
{
  __shared__ __align__(16) unsigned char sm[16384 + 16384];
  unsigned char* zb  = sm;                             // bf16 z, swizzled
  unsigned char* Pl0 = sm + 16384;                     // P dbuf, swizzled
  float* denomW = (float*)(sm + 16384);                // reuse P: [4][32]
  float* denomF = (float*)(sm + 16384 + 512);          // [32]
  float* lsumW  = (float*)(sm + 16384 + 512 + 128);    // [4]

  const int tid  = threadIdx.x;
  const int lane = tid & 63;
  const int wv   = tid >> 6;        // wave 0..3
  const int col  = lane & 15;
  const int hi   = lane >> 4;       // 0..3
  const int b16g = blockIdx.x * 16; // G0 row base

  // ---- stage z: 32 C-rows fp32 -> bf16 swizzled zb ----
  #pragma unroll
  for (int j = 0; j < 4; ++j) {
    int lin = j*256 + tid;              // 0..1023 float8-chunks
    int row = lin >> 5;                 // 0..31
    int c8  = lin & 31;
    int grow = b16g + (row >> 1) + (row & 1) * 16384;
    const float4* src = reinterpret_cast<const float4*>(z + (size_t)grow*256 + c8*8);
    float4 v0 = src[0], v1 = src[1];
    uint32_t w0 = (uint32_t)f2bf(v0.x) | ((uint32_t)f2bf(v0.y) << 16);
    uint32_t w1 = (uint32_t)f2bf(v0.z) | ((uint32_t)f2bf(v0.w) << 16);
    uint32_t w2 = (uint32_t)f2bf(v1.x) | ((uint32_t)f2bf(v1.y) << 16);
    uint32_t w3 = (uint32_t)f2bf(v1.z) | ((uint32_t)f2bf(v1.w) << 16);
    int boff = (row*512 + c8*16) ^ ((row & 7) << 4);
    uint32_t* p = reinterpret_cast<uint32_t*>(zb + boff);
    p[0] = w0; p[1] = w1; p[2] = w2; p[3] = w3;
  }
  __syncthreads();

  f32x4 accQ[2][4] = {};      // 2 row-tiles x 4 d-col-tiles (32 regs)
  float dn[2][4] = {};        // denominator partials
  float lsum = 0.0f;

  #pragma unroll 1
  for (int kt = 0; kt < 8; ++kt) {
    const int ke0 = kt*128 + wv*32;     // this wave's 32-wide k-stripe
    unsigned char* Pl = Pl0 + (kt & 1)*8192;

    // ---- region 1: mb batch-0 + enorms + ciphers + m1 (2 kc passes) ----
    const unsigned short* eb0 = Eb + (size_t)(ke0 + col)*256 + hi*8;
    const unsigned short* eb1 = eb0 + 16*256;
    bf16x8 mb[8];
    #pragma unroll
    for (int kk = 0; kk < 8; ++kk)
      mb[kk] = *reinterpret_cast<const bf16x8*>(eb0 + kk*32);

    float enk0 = enorm[ke0 + col];
    float enk1 = enorm[ke0 + 16 + col];

    TF2 c[2][2][2];           // (row-tile, kc, pair) — pure VALU, covers mb
    #pragma unroll
    for (int rt = 0; rt < 2; ++rt)
      #pragma unroll
      for (int kc = 0; kc < 2; ++kc)
        #pragma unroll
        for (int p = 0; p < 2; ++p) {
          uint32_t t0 = (uint32_t)(b16g + rt*8 + hi*2 + p);
          uint32_t idx = t0*1024u + (uint32_t)(ke0 + kc*16 + col);
          c[rt][kc][p] = tf2x32(GKEY.a, GKEY.b, idx, idx + (1u<<24));
        }

    f32x4 aS[2][2] = {};      // (row-tile, kc)
    __builtin_amdgcn_s_setprio(1);
    #pragma unroll
    for (int kk = 0; kk < 8; ++kk) {
      #pragma unroll
      for (int rt = 0; rt < 2; ++rt) {
        int arow = rt*16 + col;
        int aoff = (arow*512 + kk*64 + hi*16) ^ ((arow & 7) << 4);
        bf16x8 af = *reinterpret_cast<const bf16x8*>(zb + aoff);
        aS[rt][0] = MFMA16(af, mb[kk], aS[rt][0]);
      }
    }
    __builtin_amdgcn_s_setprio(0);
    #pragma unroll
    for (int kk = 0; kk < 8; ++kk)                 // mb batch-1 (reuses regs)
      mb[kk] = *reinterpret_cast<const bf16x8*>(eb1 + kk*32);
    __builtin_amdgcn_s_setprio(1);
    #pragma unroll
    for (int kk = 0; kk < 8; ++kk) {
      #pragma unroll
      for (int rt = 0; rt < 2; ++rt) {
        int arow = rt*16 + col;
        int aoff = (arow*512 + kk*64 + hi*16) ^ ((arow & 7) << 4);
        bf16x8 af = *reinterpret_cast<const bf16x8*>(zb + aoff);
        aS[rt][1] = MFMA16(af, mb[kk], aS[rt][1]);
      }
    }
    __builtin_amdgcn_s_setprio(0);

    // ---- region 2: nbA loads (ct 0,1) + exp/gumbel/store-P ----
    const unsigned short* etb = ETb + (size_t)(wv*64 + col)*1024 + kt*128 + hi*8;
    bf16x8 nbA[8];
    #pragma unroll
    for (int kk = 0; kk < 4; ++kk) {
      nbA[kk]   = *reinterpret_cast<const bf16x8*>(etb + kk*32);            // ct0
      nbA[kk+4] = *reinterpret_cast<const bf16x8*>(etb + 16*1024 + kk*32);  // ct1
    }

    #pragma unroll
    for (int rt = 0; rt < 2; ++rt) {
      #pragma unroll
      for (int kc = 0; kc < 2; ++kc) {
        float enk = kc ? enk1 : enk0;
        int kl2 = (wv*32 + kc*16 + col)*2;
        #pragma unroll
        for (int rg = 0; rg < 4; ++rg) {
          int row = rt*16 + hi*4 + rg;
          uint32_t bits = (rg & 1) ? c[rt][kc][rg>>1].b : c[rt][kc][rg>>1].a;
          float pv = __expf(2.0f*aS[rt][kc][rg] - enk) * gumbel_w(bits);
          dn[rt][rg] += pv;
          *(unsigned short*)(Pl + ((row*256 + kl2) ^ ((row & 7) << 4))) = f2bf(pv);
        }
      }
    }
    __syncthreads();

    // ---- region 3: nbB issue + m2 (2 halves) ----
    bf16x8 nbB[8];
    #pragma unroll
    for (int kk = 0; kk < 4; ++kk) {
      nbB[kk]   = *reinterpret_cast<const bf16x8*>(etb + 32*1024 + kk*32);  // ct2
      nbB[kk+4] = *reinterpret_cast<const bf16x8*>(etb + 48*1024 + kk*32);  // ct3
    }
    __builtin_amdgcn_s_setprio(1);
    #pragma unroll
    for (int kk = 0; kk < 4; ++kk) {
      #pragma unroll
      for (int rt = 0; rt < 2; ++rt) {
        int prow = rt*16 + col;
        int poff = (prow*256 + kk*64 + hi*16) ^ ((prow & 7) << 4);
        bf16x8 af = *reinterpret_cast<const bf16x8*>(Pl + poff);
        accQ[rt][0] = MFMA16(af, nbA[kk],   accQ[rt][0]);
        accQ[rt][1] = MFMA16(af, nbA[kk+4], accQ[rt][1]);
        accQ[rt][2] = MFMA16(af, nbB[kk],   accQ[rt][2]);
        accQ[rt][3] = MFMA16(af, nbB[kk+4], accQ[rt][3]);
      }
    }
    __builtin_amdgcn_s_setprio(0);
    // no second barrier: next iteration writes the other P buffer
  }
  __syncthreads();   // protect reduction-scratch reuse of Pl

  // ---- denominator: reduce over 16 col-lanes, then 4 waves via LDS ----
  #pragma unroll
  for (int rt = 0; rt < 2; ++rt)
    #pragma unroll
    for (int rg = 0; rg < 4; ++rg) {
      float v = dn[rt][rg];
      v += __shfl_xor(v, 1);
      v += __shfl_xor(v, 2);
      v += __shfl_xor(v, 4);
      v += __shfl_xor(v, 8);
      dn[rt][rg] = v;
    }
  if (col == 0) {
    #pragma unroll
    for (int rt = 0; rt < 2; ++rt)
      #pragma unroll
      for (int rg = 0; rg < 4; ++rg)
        denomW[wv*32 + rt*16 + hi*4 + rg] = dn[rt][rg];
  }
  __syncthreads();
  if (tid < 32) {
    float s = denomW[tid] + denomW[32+tid] + denomW[64+tid] + denomW[96+tid];
    denomF[tid] = __builtin_amdgcn_rcpf(s);
  }
  __syncthreads();

  // ---- epilogue: normalize, write out0, loss partial ----
  #pragma unroll
  for (int rt = 0; rt < 2; ++rt) {
    #pragma unroll
    for (int rg = 0; rg < 4; ++rg) {
      int row = rt*16 + hi*4 + rg;
      float rd = denomF[row];
      int grow = b16g + (row >> 1) + (row & 1)*16384;
      float* orow = out + (size_t)grow*256;
      const float* zrow = z + (size_t)grow*256;
      #pragma unroll
      for (int ct = 0; ct < 4; ++ct) {
        int d = wv*64 + ct*16 + col;
        float q  = accQ[rt][ct][rg] * rd;
        float zv = zrow[d];
        float df = q - zv;
        orow[d] = zv + df;          // straight-through value == quantized
        lsum += df*df;
      }
    }
  }
  #pragma unroll
  for (int o = 32; o > 0; o >>= 1) lsum += __shfl_down(lsum, o);
  if (lane == 0) lsumW[wv] = lsum;
  __syncthreads();
  if (tid == 0) {
    partials[blockIdx.x] = lsumW[0] + lsumW[1] + lsumW[2] + lsumW[3];
  }
}

// ---------------------------------------------------------------------------
// Final: loss = 1.25 * sum(partials[0..1024)) / 2^23
// ---------------------------------------------------------------------------
__global__ void gq_final(const float* __restrict__ partials, float* __restrict__ out)
{
  const int t = threadIdx.x;   // 512
  float v = partials[t] + partials[t + 512];
  #pragma unroll
  for (int o = 32; o > 0; o >>= 1) v += __shfl_down(v, o);
  __shared__ float ws8[8];
  if ((t & 63) == 0) ws8[t >> 6] = v;
  __syncthreads();
  if (t == 0) {
    float s = 0.f;
    #pragma unroll
    for (int i = 0; i < 8; ++i) s += ws8[i];
    out[8388608] = 1.25f * s * (1.0f / 8388608.0f);
  }
}

extern "C" void kernel_launch(void* const* d_in, const int* in_sizes, int n_in,
                              void* d_out, int out_size, void* d_ws, size_t ws_size,
                              hipStream_t stream)
{
  const float* z   = (const float*)d_in[0];   // [32,1024,256]
  const float* emb = (const float*)d_in[1];   // [1024,256]
  float* out = (float*)d_out;                 // 8388608 + 1
  char* ws = (char*)d_ws;
  unsigned short* Eb  = (unsigned short*)ws;               // 524288 B
  unsigned short* ETb = (unsigned short*)(ws + 524288);    // 524288 B
  float* enorm    = (float*)(ws + 1048576);                // 4096 B
  float* partials = (float*)(ws + 1048576 + 4096);         // 4096 B

  gq_prep<<<1024, 256, 0, stream>>>(emb, Eb, ETb, enorm);
  gq_main<<<1024, 256, 0, stream>>>(z, Eb, ETb, enorm, out, partials);
  gq_final<<<1, 512, 0, stream>>>(partials, out);
}

// Round 13
// 100.147 us; speedup vs baseline: 1.8139x; 1.3428x over previous
//
#include <hip/hip_runtime.h>
#include <hip/hip_bf16.h>
#include <stdint.h>

// ---------------------------------------------------------------------------
// GumbelQuantizer: z[32768,256] fp32, emb[1024,256] fp32 ->
//   out0 = softmax((-d + gumbel)) @ emb  (straight-through == quantized)
//   out1 = 1.25 * mean((quantized - z)^2)
// s_k = 2 z.e_k - |e_k|^2 (row-constant -|z|^2 cancels). Gumbel via exact JAX
// threefry2x32; e^g = rcp(-log2 u) (global 1/ln2 cancels in softmax).
//
// R13: cipher-into-m2 software pipeline on the R7 base (92.5us best).
// R7's m2 = 32 MFMAs ~155cy with ~120 unused VALU issue slots/wave-tile;
// the 576-inst cipher burst sits serial elsewhere. R9 failed this idea by
// placing ciphers between setprio fences (in-order issue delayed MFMAs).
// R13: ciphers(kt) INSIDE m2(kt-1)'s kk-loop body, same BB, no setprio on
// m2 -> scheduler fills MFMA dep-stalls with cipher VALU. Per tile kt>=1:
//   mb_load(kt) -> { m2(kt-1) x8 MFMA + 2 cipher-pairs per kk } ->
//   m1(kt) -> nb_load(kt) -> exp/store P[kt&1] -> barrier
// Peel tile 0 (=R7 region1-2), trailing m2(7). Peak ~120 VGPR under the
// (512,2)=128 budget (R5/R8/R11 lesson: budget = 256/arg2; spill shows as
// FETCH blowup -> tripwire).
// ---------------------------------------------------------------------------

typedef __bf16 bf16x8 __attribute__((ext_vector_type(8)));
typedef float  f32x4  __attribute__((ext_vector_type(4)));

#define MFMA16(A,B,C) __builtin_amdgcn_mfma_f32_16x16x32_bf16((A),(B),(C),0,0,0)

struct TF2 { uint32_t a, b; };

__host__ __device__ constexpr uint32_t rotl32(uint32_t v, int r){ return (v<<r)|(v>>(32-r)); }

// Threefry-2x32, 20 rounds — exact JAX implementation.
__host__ __device__ constexpr TF2 tf2x32(uint32_t k0, uint32_t k1, uint32_t x0, uint32_t x1){
  const uint32_t k2 = k0 ^ k1 ^ 0x1BD11BDAu;
  x0 += k0; x1 += k1;
  x0 += x1; x1 = rotl32(x1,13); x1 ^= x0;
  x0 += x1; x1 = rotl32(x1,15); x1 ^= x0;
  x0 += x1; x1 = rotl32(x1,26); x1 ^= x0;
  x0 += x1; x1 = rotl32(x1, 6); x1 ^= x0;
  x0 += k1; x1 += k2 + 1u;
  x0 += x1; x1 = rotl32(x1,17); x1 ^= x0;
  x0 += x1; x1 = rotl32(x1,29); x1 ^= x0;
  x0 += x1; x1 = rotl32(x1,16); x1 ^= x0;
  x0 += x1; x1 = rotl32(x1,24); x1 ^= x0;
  x0 += k2; x1 += k0 + 2u;
  x0 += x1; x1 = rotl32(x1,13); x1 ^= x0;
  x0 += x1; x1 = rotl32(x1,15); x1 ^= x0;
  x0 += x1; x1 = rotl32(x1,26); x1 ^= x0;
  x0 += x1; x1 = rotl32(x1, 6); x1 ^= x0;
  x0 += k0; x1 += k1 + 3u;
  x0 += x1; x1 = rotl32(x1,17); x1 ^= x0;
  x0 += x1; x1 = rotl32(x1,29); x1 ^= x0;
  x0 += x1; x1 = rotl32(x1,16); x1 ^= x0;
  x0 += x1; x1 = rotl32(x1,24); x1 ^= x0;
  x0 += k1; x1 += k2 + 4u;
  x0 += x1; x1 = rotl32(x1,13); x1 ^= x0;
  x0 += x1; x1 = rotl32(x1,15); x1 ^= x0;
  x0 += x1; x1 = rotl32(x1,26); x1 ^= x0;
  x0 += x1; x1 = rotl32(x1, 6); x1 ^= x0;
  x0 += k2; x1 += k0 + 5u;
  return {x0, x1};
}

// gkey = fold_in(key(0), 1) = threefry((0,0), (0,1)) — compile-time.
constexpr TF2 GKEY = tf2x32(0u, 0u, 0u, 1u);

__device__ __forceinline__ unsigned short f2bf(float f){
  __bf16 h = (__bf16)f;
  return __builtin_bit_cast(unsigned short, h);
}

// exp(gumbel) up to a global constant: 1/(-log2 u), u = JAX uniform(tiny,1)
__device__ __forceinline__ float gumbel_w(uint32_t bits){
  float uf = __uint_as_float((bits >> 9) | 0x3f800000u) - 1.0f;
  float u  = fmaxf(uf, 1.17549435e-38f);
  return __builtin_amdgcn_rcpf(-__log2f(u));
}

// ---------------------------------------------------------------------------
// Prep: bf16 E [1024][256], bf16 E^T [256][1024], |e_k|^2 fp32 [1024]
// ---------------------------------------------------------------------------
__global__ void gq_prep(const float* __restrict__ emb, unsigned short* __restrict__ Eb,
                        unsigned short* __restrict__ ETb, float* __restrict__ enorm)
{
  const int r = blockIdx.x;       // 1024 emb rows
  const int t = threadIdx.x;      // 256 threads = one row
  float e = emb[r*256 + t];
  unsigned short h = f2bf(e);
  Eb[r*256 + t] = h;
  ETb[t*1024 + r] = h;
  float sq = e*e;
  #pragma unroll
  for (int o = 32; o > 0; o >>= 1) sq += __shfl_down(sq, o);
  __shared__ float ws4[4];
  if ((t & 63) == 0) ws4[t >> 6] = sq;
  __syncthreads();
  if (t == 0) enorm[r] = ws4[0] + ws4[1] + ws4[2] + ws4[3];
}

// ---------------------------------------------------------------------------
// Main fused kernel: 512 blocks x 512 threads (8 waves), 2 blocks/CU.
// Block b owns z rows [b*32, b*32+32) (G0) and +16384 (G1) — threefry pairs.
// LDS: zb  = bf16 z [64][256] XOR-swizzled        32768 B
//      Pl  = bf16 P [2][64][128] XOR-swizzled     32768 B (double-buffered)
// Wave w owns emb-col stripe w*16 within each 128-wide k-tile (matmul 1)
// and d-cols [w*32, w*32+32) of the output (matmul 2).
// ---------------------------------------------------------------------------
__global__ __launch_bounds__(512, 2)   // empirically: 128-VGPR budget
void gq_main(
    const float* __restrict__ z, const unsigned short* __restrict__ Eb,
    const unsigned short* __restrict__ ETb, const float* __restrict__ enorm,
    float* __restrict__ out, float* __restrict__ partials)
{
  __shared__ __align__(16) unsigned char sm[32768 + 32768];
  unsigned char* zb  = sm;                             // bf16 z, swizzled
  unsigned char* Pl0 = sm + 32768;                     // bf16 P, dbuf, swizzled
  float* denomW = (float*)(sm + 32768);                // reuse: [8][64]
  float* denomF = (float*)(sm + 32768 + 2048);         // [64]
  float* lsumW  = (float*)(sm + 32768 + 2048 + 256);   // [8]

  const int tid  = threadIdx.x;
  const int lane = tid & 63;
  const int wv   = tid >> 6;        // wave 0..7
  const int col  = lane & 15;
  const int hi   = lane >> 4;       // 0..3
  const int b32  = blockIdx.x * 32;

  // ---- stage z: fp32 -> bf16 swizzled LDS ----
  #pragma unroll
  for (int j = 0; j < 8; ++j) {
    int lin = j*512 + tid;              // 0..4095 float4s
    int row = lin >> 6;                 // 0..63
    int c4  = lin & 63;
    int grow = (row < 32) ? (b32 + row) : (16384 + b32 + row - 32);
    float4 v = *(reinterpret_cast<const float4*>(z + (size_t)grow*256) + c4);
    uint32_t lo = (uint32_t)f2bf(v.x) | ((uint32_t)f2bf(v.y) << 16);
    uint32_t h2 = (uint32_t)f2bf(v.z) | ((uint32_t)f2bf(v.w) << 16);
    int boff = (row*512 + c4*8) ^ ((row & 7) << 4);
    uint32_t* p = reinterpret_cast<uint32_t*>(zb + boff);
    p[0] = lo; p[1] = h2;
  }
  __syncthreads();

  f32x4 accQ[4][2] = {};      // Q accumulator: 4 row-tiles x 2 d-col-tiles
  float dn[4][4] = {};        // denominator partials per (row-tile, reg)
  float lsum = 0.0f;

  // persistent pipeline registers
  bf16x8 mb[8];               // m1 B-frags (current tile)
  bf16x8 nb[8];               // m2 B-frags (tile of the pending m2)
  TF2 c[2][4];                // ciphers for the current tile

  auto load_mb = [&](int kt) {
    const int ke0 = kt*128 + wv*16;
    const unsigned short* ebase = Eb + (size_t)(ke0 + col)*256 + hi*8;
    #pragma unroll
    for (int kk = 0; kk < 8; ++kk)
      mb[kk] = *reinterpret_cast<const bf16x8*>(ebase + kk*32);
  };

  auto load_nb = [&](int kt) {
    const unsigned short* etb0 = ETb + (size_t)(wv*32 + col)*1024 + kt*128 + hi*8;
    const unsigned short* etb1 = etb0 + 16*1024;
    #pragma unroll
    for (int kk = 0; kk < 4; ++kk) {
      nb[kk]   = *reinterpret_cast<const bf16x8*>(etb0 + kk*32);
      nb[kk+4] = *reinterpret_cast<const bf16x8*>(etb1 + kk*32);
    }
  };

  auto ciphers_all = [&](int kt) {       // prologue only
    const int ke0 = kt*128 + wv*16;
    #pragma unroll
    for (int rt = 0; rt < 2; ++rt)
      #pragma unroll
      for (int rg = 0; rg < 4; ++rg) {
        int rowL = rt*16 + hi*4 + rg;
        uint32_t idx = (uint32_t)(b32 + rowL)*1024u + (uint32_t)(ke0 + col);
        c[rt][rg] = tf2x32(GKEY.a, GKEY.b, idx, idx + (1u<<24));
      }
  };

  auto m1_mfma = [&](f32x4 (&aS)[4]) {   // S = Zbf16 @ E^T using mb
    __builtin_amdgcn_s_setprio(1);
    #pragma unroll
    for (int kk = 0; kk < 8; ++kk) {
      #pragma unroll
      for (int rt = 0; rt < 4; ++rt) {
        int arow = rt*16 + col;
        int aoff = (arow*512 + kk*64 + hi*16) ^ ((arow & 7) << 4);
        bf16x8 af = *reinterpret_cast<const bf16x8*>(zb + aoff);
        aS[rt] = MFMA16(af, mb[kk], aS[rt]);
      }
    }
    __builtin_amdgcn_s_setprio(0);
  };

  auto exp_store = [&](f32x4 (&aS)[4], int kt, unsigned char* Pl) {
    const int ke0 = kt*128 + wv*16;
    float enk = enorm[ke0 + col];
    #pragma unroll
    for (int rt = 0; rt < 2; ++rt) {
      #pragma unroll
      for (int rg = 0; rg < 4; ++rg) {
        int rowL = rt*16 + hi*4 + rg;
        float p0 = __expf(2.0f*aS[rt  ][rg] - enk) * gumbel_w(c[rt][rg].a);
        float p1 = __expf(2.0f*aS[rt+2][rg] - enk) * gumbel_w(c[rt][rg].b);
        dn[rt  ][rg] += p0;
        dn[rt+2][rg] += p1;
        int cl2  = (wv*16 + col)*2;
        int rowH = rowL + 32;
        *(unsigned short*)(Pl + ((rowL*256 + cl2) ^ ((rowL&7)<<4))) = f2bf(p0);
        *(unsigned short*)(Pl + ((rowH*256 + cl2) ^ ((rowH&7)<<4))) = f2bf(p1);
      }
    }
  };

  // m2(prev tile) MFMAs interleaved with ciphers(cur tile) — same BB,
  // NO setprio fences: scheduler fills MFMA dep-stalls with cipher VALU.
  auto m2_cipher = [&](const unsigned char* Pprev, int ktCur) {
    const int ke0c = ktCur*128 + wv*16;
    #pragma unroll
    for (int kk = 0; kk < 4; ++kk) {
      #pragma unroll
      for (int rt = 0; rt < 4; ++rt) {
        int prow = rt*16 + col;
        int poff = (prow*256 + kk*64 + hi*16) ^ ((prow&7)<<4);
        bf16x8 af = *reinterpret_cast<const bf16x8*>(Pprev + poff);
        accQ[rt][0] = MFMA16(af, nb[kk],   accQ[rt][0]);
        accQ[rt][1] = MFMA16(af, nb[kk+4], accQ[rt][1]);
      }
      // 2 cipher pairs for tile ktCur (static indices — rule #20)
      const int rtc = kk >> 1;
      #pragma unroll
      for (int q = 0; q < 2; ++q) {
        int rg = (kk & 1)*2 + q;
        int rowL = rtc*16 + hi*4 + rg;
        uint32_t idx = (uint32_t)(b32 + rowL)*1024u + (uint32_t)(ke0c + col);
        c[rtc][rg] = tf2x32(GKEY.a, GKEY.b, idx, idx + (1u<<24));
      }
    }
  };

  auto m2_plain = [&](const unsigned char* Pprev) {
    __builtin_amdgcn_s_setprio(1);
    #pragma unroll
    for (int kk = 0; kk < 4; ++kk) {
      #pragma unroll
      for (int rt = 0; rt < 4; ++rt) {
        int prow = rt*16 + col;
        int poff = (prow*256 + kk*64 + hi*16) ^ ((prow&7)<<4);
        bf16x8 af = *reinterpret_cast<const bf16x8*>(Pprev + poff);
        accQ[rt][0] = MFMA16(af, nb[kk],   accQ[rt][0]);
        accQ[rt][1] = MFMA16(af, nb[kk+4], accQ[rt][1]);
      }
    }
    __builtin_amdgcn_s_setprio(0);
  };

  // ---- peeled tile 0 (== R7's region 1+2) ----
  {
    load_mb(0);
    ciphers_all(0);                // covers mb L2 latency
    f32x4 aS[4] = {};
    m1_mfma(aS);
    load_nb(0);
    exp_store(aS, 0, Pl0);         // P[0]
  }
  __syncthreads();

  // ---- pipelined tiles 1..7 ----
  #pragma unroll 1
  for (int kt = 1; kt < 8; ++kt) {
    unsigned char* Pprev = Pl0 + ((kt-1) & 1)*16384;
    unsigned char* Pcur  = Pl0 + (kt & 1)*16384;
    load_mb(kt);                   // 8 VMEM issued first, land under m2+ciphers
    m2_cipher(Pprev, kt);          // m2(kt-1) MFMA  ||  ciphers(kt) VALU
    f32x4 aS[4] = {};
    m1_mfma(aS);                   // consumes mb
    load_nb(kt);                   // overwrites nb (m2 done with it)
    exp_store(aS, kt, Pcur);       // consumes c
    __syncthreads();
  }
  m2_plain(Pl0 + 16384);           // m2(7), P[1]
  __syncthreads();   // protect reduction-scratch reuse of Pl

  // ---- denominator: reduce over 16 lanes (this wave's cols), then 8 waves ----
  #pragma unroll
  for (int rt = 0; rt < 4; ++rt)
    #pragma unroll
    for (int rg = 0; rg < 4; ++rg) {
      float v = dn[rt][rg];
      v += __shfl_xor(v, 1);
      v += __shfl_xor(v, 2);
      v += __shfl_xor(v, 4);
      v += __shfl_xor(v, 8);
      dn[rt][rg] = v;
    }
  if (col == 0) {
    #pragma unroll
    for (int rt = 0; rt < 4; ++rt)
      #pragma unroll
      for (int rg = 0; rg < 4; ++rg)
        denomW[wv*64 + rt*16 + hi*4 + rg] = dn[rt][rg];
  }
  __syncthreads();
  if (tid < 64) {
    float s = 0.f;
    #pragma unroll
    for (int w2 = 0; w2 < 8; ++w2) s += denomW[w2*64 + tid];
    denomF[tid] = __builtin_amdgcn_rcpf(s);
  }
  __syncthreads();

  // ---- epilogue: normalize, write out0, accumulate loss partial ----
  #pragma unroll
  for (int rt = 0; rt < 4; ++rt) {
    #pragma unroll
    for (int rg = 0; rg < 4; ++rg) {
      int row = rt*16 + hi*4 + rg;
      float rd = denomF[row];
      int grow = (row < 32) ? (b32 + row) : (16384 + b32 + row - 32);
      float* orow = out + (size_t)grow*256;
      const float* zrow = z + (size_t)grow*256;
      #pragma unroll
      for (int ct = 0; ct < 2; ++ct) {
        int d = wv*32 + ct*16 + col;
        float q  = accQ[rt][ct][rg] * rd;
        float zv = zrow[d];
        float df = q - zv;
        orow[d] = zv + df;          // straight-through value == quantized
        lsum += df*df;
      }
    }
  }
  #pragma unroll
  for (int o = 32; o > 0; o >>= 1) lsum += __shfl_down(lsum, o);
  if (lane == 0) lsumW[wv] = lsum;
  __syncthreads();
  if (tid == 0) {
    float s = 0.f;
    #pragma unroll
    for (int w2 = 0; w2 < 8; ++w2) s += lsumW[w2];
    partials[blockIdx.x] = s;
  }
}

// ---------------------------------------------------------------------------
// Final: loss = 1.25 * sum(partials) / 2^23
// ---------------------------------------------------------------------------
__global__ void gq_final(const float* __restrict__ partials, float* __restrict__ out)
{
  const int t = threadIdx.x;   // 512
  float v = partials[t];
  #pragma unroll
  for (int o = 32; o > 0; o >>= 1) v += __shfl_down(v, o);
  __shared__ float ws8[8];
  if ((t & 63) == 0) ws8[t >> 6] = v;
  __syncthreads();
  if (t == 0) {
    float s = 0.f;
    #pragma unroll
    for (int i = 0; i < 8; ++i) s += ws8[i];
    out[8388608] = 1.25f * s * (1.0f / 8388608.0f);
  }
}

extern "C" void kernel_launch(void* const* d_in, const int* in_sizes, int n_in,
                              void* d_out, int out_size, void* d_ws, size_t ws_size,
                              hipStream_t stream)
{
  const float* z   = (const float*)d_in[0];   // [32,1024,256]
  const float* emb = (const float*)d_in[1];   // [1024,256]
  float* out = (float*)d_out;                 // 8388608 + 1
  char* ws = (char*)d_ws;
  unsigned short* Eb  = (unsigned short*)ws;               // 524288 B
  unsigned short* ETb = (unsigned short*)(ws + 524288);    // 524288 B
  float* enorm    = (float*)(ws + 1048576);                // 4096 B
  float* partials = (float*)(ws + 1048576 + 4096);         // 2048 B

  gq_prep<<<1024, 256, 0, stream>>>(emb, Eb, ETb, enorm);
  gq_main<<<512, 512, 0, stream>>>(z, Eb, ETb, enorm, out, partials);
  gq_final<<<1, 512, 0, stream>>>(partials, out);
}

// Round 14
// 90.909 us; speedup vs baseline: 1.9982x; 1.1016x over previous
//
#include <hip/hip_runtime.h>
#include <hip/hip_bf16.h>
#include <stdint.h>

// ---------------------------------------------------------------------------
// GumbelQuantizer: z[32768,256] fp32, emb[1024,256] fp32 ->
//   out0 = softmax((-d + gumbel)) @ emb  (straight-through == quantized)
//   out1 = 1.25 * mean((quantized - z)^2)
// s_k = 2 z.e_k - |e_k|^2 (row-constant -|z|^2 cancels). Gumbel via exact JAX
// threefry2x32; e^g = rcp(-log2 u) (global 1/ln2 cancels in softmax).
//
// R14: zero-VALU LDS addressing (R7 base, layout-only change). R7 spent
// ~150 VALU/tile-wave on ds addresses (XOR swizzle unfoldable into offset
// immediates). New unit-major layouts:
//   zb3[kk][hi][row] x16B : m1 reads = ONE base reg (hi*1024+col*16) +
//                           compile-time offset (kk*4096+rt*256)
//   Pl2[kk][hi][row] x16B : m2 reads same base + imm; P-stores = one
//                           per-tile base + imm (rt*256+rg*16+{0,512})
// Per-phase banks: read slot = row%8 = col&7 -> conflict-free, no XOR.
// Region order / barriers / setprio / ciphers byte-identical to R7 (every
// reorder R8/R9/R13 regressed; m114: overlap comes from wave co-scheduling).
// ---------------------------------------------------------------------------

typedef __bf16 bf16x8 __attribute__((ext_vector_type(8)));
typedef float  f32x4  __attribute__((ext_vector_type(4)));

#define MFMA16(A,B,C) __builtin_amdgcn_mfma_f32_16x16x32_bf16((A),(B),(C),0,0,0)

struct TF2 { uint32_t a, b; };

__host__ __device__ constexpr uint32_t rotl32(uint32_t v, int r){ return (v<<r)|(v>>(32-r)); }

// Threefry-2x32, 20 rounds — exact JAX implementation.
__host__ __device__ constexpr TF2 tf2x32(uint32_t k0, uint32_t k1, uint32_t x0, uint32_t x1){
  const uint32_t k2 = k0 ^ k1 ^ 0x1BD11BDAu;
  x0 += k0; x1 += k1;
  x0 += x1; x1 = rotl32(x1,13); x1 ^= x0;
  x0 += x1; x1 = rotl32(x1,15); x1 ^= x0;
  x0 += x1; x1 = rotl32(x1,26); x1 ^= x0;
  x0 += x1; x1 = rotl32(x1, 6); x1 ^= x0;
  x0 += k1; x1 += k2 + 1u;
  x0 += x1; x1 = rotl32(x1,17); x1 ^= x0;
  x0 += x1; x1 = rotl32(x1,29); x1 ^= x0;
  x0 += x1; x1 = rotl32(x1,16); x1 ^= x0;
  x0 += x1; x1 = rotl32(x1,24); x1 ^= x0;
  x0 += k2; x1 += k0 + 2u;
  x0 += x1; x1 = rotl32(x1,13); x1 ^= x0;
  x0 += x1; x1 = rotl32(x1,15); x1 ^= x0;
  x0 += x1; x1 = rotl32(x1,26); x1 ^= x0;
  x0 += x1; x1 = rotl32(x1, 6); x1 ^= x0;
  x0 += k0; x1 += k1 + 3u;
  x0 += x1; x1 = rotl32(x1,17); x1 ^= x0;
  x0 += x1; x1 = rotl32(x1,29); x1 ^= x0;
  x0 += x1; x1 = rotl32(x1,16); x1 ^= x0;
  x0 += x1; x1 = rotl32(x1,24); x1 ^= x0;
  x0 += k1; x1 += k2 + 4u;
  x0 += x1; x1 = rotl32(x1,13); x1 ^= x0;
  x0 += x1; x1 = rotl32(x1,15); x1 ^= x0;
  x0 += x1; x1 = rotl32(x1,26); x1 ^= x0;
  x0 += x1; x1 = rotl32(x1, 6); x1 ^= x0;
  x0 += k2; x1 += k0 + 5u;
  return {x0, x1};
}

// gkey = fold_in(key(0), 1) = threefry((0,0), (0,1)) — compile-time.
constexpr TF2 GKEY = tf2x32(0u, 0u, 0u, 1u);

__device__ __forceinline__ unsigned short f2bf(float f){
  __bf16 h = (__bf16)f;
  return __builtin_bit_cast(unsigned short, h);
}

// exp(gumbel) up to a global constant: 1/(-log2 u), u = JAX uniform(tiny,1)
__device__ __forceinline__ float gumbel_w(uint32_t bits){
  float uf = __uint_as_float((bits >> 9) | 0x3f800000u) - 1.0f;
  float u  = fmaxf(uf, 1.17549435e-38f);
  return __builtin_amdgcn_rcpf(-__log2f(u));
}

// ---------------------------------------------------------------------------
// Prep: bf16 E [1024][256], bf16 E^T [256][1024], |e_k|^2 fp32 [1024]
// ---------------------------------------------------------------------------
__global__ void gq_prep(const float* __restrict__ emb, unsigned short* __restrict__ Eb,
                        unsigned short* __restrict__ ETb, float* __restrict__ enorm)
{
  const int r = blockIdx.x;       // 1024 emb rows
  const int t = threadIdx.x;      // 256 threads = one row
  float e = emb[r*256 + t];
  unsigned short h = f2bf(e);
  Eb[r*256 + t] = h;
  ETb[t*1024 + r] = h;
  float sq = e*e;
  #pragma unroll
  for (int o = 32; o > 0; o >>= 1) sq += __shfl_down(sq, o);
  __shared__ float ws4[4];
  if ((t & 63) == 0) ws4[t >> 6] = sq;
  __syncthreads();
  if (t == 0) enorm[r] = ws4[0] + ws4[1] + ws4[2] + ws4[3];
}

// ---------------------------------------------------------------------------
// Main fused kernel: 512 blocks x 512 threads (8 waves), 2 blocks/CU.
// Block b owns z rows [b*32, b*32+32) (G0) and +16384 (G1) — threefry pairs.
// LDS layout (unit-major, 16B units):
//   zb3  at [0, 32768):       unit(kk 0..7, hi 0..3, row 0..63) =
//                             z[row][kk*32+hi*8 .. +7] bf16
//                             byte = kk*4096 + hi*1024 + row*16
//   Pl2  at [32768, 65536):   2 buffers x 16KB; unit(kk 0..3, hi, row) =
//                             P[row][kk*32+hi*8 .. +7] bf16
// All ds accesses: one lane-resident base reg + compile-time offset.
// Wave w owns emb-col stripe w*16 per 128-k tile (m1/gumbel) and d-cols
// [w*32,+32) of the output (m2).
// ---------------------------------------------------------------------------
__global__ __launch_bounds__(512, 2)   // empirically: 128-VGPR budget
void gq_main(
    const float* __restrict__ z, const unsigned short* __restrict__ Eb,
    const unsigned short* __restrict__ ETb, const float* __restrict__ enorm,
    float* __restrict__ out, float* __restrict__ partials)
{
  __shared__ __align__(16) unsigned char sm[32768 + 32768];
  float* denomW = (float*)(sm + 32768);                // reuse Pl2: [8][64]
  float* denomF = (float*)(sm + 32768 + 2048);         // [64]
  float* lsumW  = (float*)(sm + 32768 + 2048 + 256);   // [8]

  const int tid  = threadIdx.x;
  const int lane = tid & 63;
  const int wv   = tid >> 6;        // wave 0..7
  const int col  = lane & 15;
  const int hi   = lane >> 4;       // 0..3
  const int b32  = blockIdx.x * 32;

  // ---- stage z: fp32 -> bf16 unit-major zb3 ----
  // thread handles (row, u): u = kk*4 + hi unit index; reads 8 floats,
  // writes one 16B unit at u*1024 + row*16.
  #pragma unroll
  for (int j = 0; j < 4; ++j) {
    int lin = j*512 + tid;              // 0..2047 units
    int row = lin >> 5;                 // 0..63
    int u   = lin & 31;                 // 0..31
    int grow = (row < 32) ? (b32 + row) : (16384 + b32 + row - 32);
    const float4* src = reinterpret_cast<const float4*>(z + (size_t)grow*256 + u*8);
    float4 v0 = src[0], v1 = src[1];
    uint32_t w0 = (uint32_t)f2bf(v0.x) | ((uint32_t)f2bf(v0.y) << 16);
    uint32_t w1 = (uint32_t)f2bf(v0.z) | ((uint32_t)f2bf(v0.w) << 16);
    uint32_t w2 = (uint32_t)f2bf(v1.x) | ((uint32_t)f2bf(v1.y) << 16);
    uint32_t w3 = (uint32_t)f2bf(v1.z) | ((uint32_t)f2bf(v1.w) << 16);
    uint32_t* p = reinterpret_cast<uint32_t*>(sm + u*1024 + row*16);
    p[0] = w0; p[1] = w1; p[2] = w2; p[3] = w3;
  }
  __syncthreads();

  f32x4 accQ[4][2] = {};      // Q accumulator: 4 row-tiles x 2 d-col-tiles
  float dn[4][4] = {};        // denominator partials per (row-tile, reg)
  float lsum = 0.0f;

  // lane-resident LDS bases (computed once)
  const unsigned char* zA = sm + (hi*1024 + col*16);            // m1 A reads
  // P store base: value (row = rt*16+hi*4+rg, k = wv*16+col) lives at
  // (k>>5)*4096 + ((k>>3)&3)*1024 + row*16 + (k&7)*2
  const int pstore_off = (wv >> 1)*4096 + ((((wv & 1) << 1) | (col >> 3)))*1024
                       + hi*64 + (col & 7)*2;

  #pragma unroll 1
  for (int kt = 0; kt < 8; ++kt) {
    const int ke0 = kt*128 + wv*16;     // this wave's emb-row base
    const int pbuf = 32768 + (kt & 1)*16384;

    // ---- region 1: mb prefetch + ciphers + m1 MFMAs ----
    const unsigned short* ebase = Eb + (size_t)(ke0 + col)*256 + hi*8;
    bf16x8 mb[8];
    #pragma unroll
    for (int kk = 0; kk < 8; ++kk)
      mb[kk] = *reinterpret_cast<const bf16x8*>(ebase + kk*32);

    float enk = enorm[ke0 + col];

    TF2 c[2][4];                       // ciphers: zero data dependencies
    #pragma unroll
    for (int rt = 0; rt < 2; ++rt) {
      #pragma unroll
      for (int rg = 0; rg < 4; ++rg) {
        int rowL = rt*16 + hi*4 + rg;                       // G0 row (0..31)
        uint32_t idx = (uint32_t)(b32 + rowL)*1024u + (uint32_t)(ke0 + col);
        c[rt][rg] = tf2x32(GKEY.a, GKEY.b, idx, idx + (1u<<24)); // (t, t+16384)
      }
    }

    f32x4 aS[4] = {};
    __builtin_amdgcn_s_setprio(1);
    #pragma unroll
    for (int kk = 0; kk < 8; ++kk) {
      #pragma unroll
      for (int rt = 0; rt < 4; ++rt) {
        bf16x8 af = *reinterpret_cast<const bf16x8*>(zA + kk*4096 + rt*256);
        aS[rt] = MFMA16(af, mb[kk], aS[rt]);
      }
    }
    __builtin_amdgcn_s_setprio(0);

    // ---- region 2: nb prefetch + exp/pack/store P ----
    const unsigned short* etb0 = ETb + (size_t)(wv*32 + col)*1024 + kt*128 + hi*8;
    const unsigned short* etb1 = etb0 + 16*1024;
    bf16x8 nb[8];
    #pragma unroll
    for (int kk = 0; kk < 4; ++kk) {
      nb[kk]   = *reinterpret_cast<const bf16x8*>(etb0 + kk*32);
      nb[kk+4] = *reinterpret_cast<const bf16x8*>(etb1 + kk*32);
    }

    unsigned char* sb = sm + pbuf + pstore_off;
    #pragma unroll
    for (int rt = 0; rt < 2; ++rt) {
      #pragma unroll
      for (int rg = 0; rg < 4; ++rg) {
        float p0 = __expf(2.0f*aS[rt  ][rg] - enk) * gumbel_w(c[rt][rg].a);
        float p1 = __expf(2.0f*aS[rt+2][rg] - enk) * gumbel_w(c[rt][rg].b);
        dn[rt  ][rg] += p0;
        dn[rt+2][rg] += p1;
        *(unsigned short*)(sb + rt*256 + rg*16)       = f2bf(p0);  // rows 0..31
        *(unsigned short*)(sb + rt*256 + rg*16 + 512) = f2bf(p1);  // rows 32..63
      }
    }
    __syncthreads();

    // ---- region 3: m2 MFMAs (P via base+imm, no global loads) ----
    const unsigned char* pA = sm + pbuf + (hi*1024 + col*16);
    __builtin_amdgcn_s_setprio(1);
    #pragma unroll
    for (int kk = 0; kk < 4; ++kk) {
      #pragma unroll
      for (int rt = 0; rt < 4; ++rt) {
        bf16x8 af = *reinterpret_cast<const bf16x8*>(pA + kk*4096 + rt*256);
        accQ[rt][0] = MFMA16(af, nb[kk],   accQ[rt][0]);
        accQ[rt][1] = MFMA16(af, nb[kk+4], accQ[rt][1]);
      }
    }
    __builtin_amdgcn_s_setprio(0);
    // no second barrier: next iteration writes the other P buffer
  }
  __syncthreads();   // protect reduction-scratch reuse of Pl2

  // ---- denominator: reduce over 16 lanes (this wave's cols), then 8 waves ----
  #pragma unroll
  for (int rt = 0; rt < 4; ++rt)
    #pragma unroll
    for (int rg = 0; rg < 4; ++rg) {
      float v = dn[rt][rg];
      v += __shfl_xor(v, 1);
      v += __shfl_xor(v, 2);
      v += __shfl_xor(v, 4);
      v += __shfl_xor(v, 8);
      dn[rt][rg] = v;
    }
  if (col == 0) {
    #pragma unroll
    for (int rt = 0; rt < 4; ++rt)
      #pragma unroll
      for (int rg = 0; rg < 4; ++rg)
        denomW[wv*64 + rt*16 + hi*4 + rg] = dn[rt][rg];
  }
  __syncthreads();
  if (tid < 64) {
    float s = 0.f;
    #pragma unroll
    for (int w2 = 0; w2 < 8; ++w2) s += denomW[w2*64 + tid];
    denomF[tid] = __builtin_amdgcn_rcpf(s);
  }
  __syncthreads();

  // ---- epilogue: normalize, write out0, accumulate loss partial ----
  #pragma unroll
  for (int rt = 0; rt < 4; ++rt) {
    #pragma unroll
    for (int rg = 0; rg < 4; ++rg) {
      int row = rt*16 + hi*4 + rg;
      float rd = denomF[row];
      int grow = (row < 32) ? (b32 + row) : (16384 + b32 + row - 32);
      float* orow = out + (size_t)grow*256;
      const float* zrow = z + (size_t)grow*256;
      #pragma unroll
      for (int ct = 0; ct < 2; ++ct) {
        int d = wv*32 + ct*16 + col;
        float q  = accQ[rt][ct][rg] * rd;
        float zv = zrow[d];
        float df = q - zv;
        orow[d] = zv + df;          // straight-through value == quantized
        lsum += df*df;
      }
    }
  }
  #pragma unroll
  for (int o = 32; o > 0; o >>= 1) lsum += __shfl_down(lsum, o);
  if (lane == 0) lsumW[wv] = lsum;
  __syncthreads();
  if (tid == 0) {
    float s = 0.f;
    #pragma unroll
    for (int w2 = 0; w2 < 8; ++w2) s += lsumW[w2];
    partials[blockIdx.x] = s;
  }
}

// ---------------------------------------------------------------------------
// Final: loss = 1.25 * sum(partials) / 2^23
// ---------------------------------------------------------------------------
__global__ void gq_final(const float* __restrict__ partials, float* __restrict__ out)
{
  const int t = threadIdx.x;   // 512
  float v = partials[t];
  #pragma unroll
  for (int o = 32; o > 0; o >>= 1) v += __shfl_down(v, o);
  __shared__ float ws8[8];
  if ((t & 63) == 0) ws8[t >> 6] = v;
  __syncthreads();
  if (t == 0) {
    float s = 0.f;
    #pragma unroll
    for (int i = 0; i < 8; ++i) s += ws8[i];
    out[8388608] = 1.25f * s * (1.0f / 8388608.0f);
  }
}

extern "C" void kernel_launch(void* const* d_in, const int* in_sizes, int n_in,
                              void* d_out, int out_size, void* d_ws, size_t ws_size,
                              hipStream_t stream)
{
  const float* z   = (const float*)d_in[0];   // [32,1024,256]
  const float* emb = (const float*)d_in[1];   // [1024,256]
  float* out = (float*)d_out;                 // 8388608 + 1
  char* ws = (char*)d_ws;
  unsigned short* Eb  = (unsigned short*)ws;               // 524288 B
  unsigned short* ETb = (unsigned short*)(ws + 524288);    // 524288 B
  float* enorm    = (float*)(ws + 1048576);                // 4096 B
  float* partials = (float*)(ws + 1048576 + 4096);         // 2048 B

  gq_prep<<<1024, 256, 0, stream>>>(emb, Eb, ETb, enorm);
  gq_main<<<512, 512, 0, stream>>>(z, Eb, ETb, enorm, out, partials);
  gq_final<<<1, 512, 0, stream>>>(partials, out);
}